// Round 4
// baseline (516.538 us; speedup 1.0000x reference)
//
#include <hip/hip_runtime.h>
#include <hip/hip_bf16.h>
#include <cstdint>
#include <cstddef>

// B=2,S=2048 -> N=4096 tokens, H=1024, F=2048, E=8, top-2 routing.
// R10: true m201-style multi-phase K-loop for both GEMMs (fine interleave:
// per phase {2 G-loads || ds_reads || 16 MFMA} with ONE counted vmcnt per
// K-tile, raw barriers, setprio around MFMA). Upgate BM=256xBN=128(dual),
// down BM=256xBN=128 with B-slab-sharing grid order. Everything else = R9.
#define N_TOK 4096
#define H_DIM 1024
#define F_DIM 2048
#define E_NUM 8
#define RCAP 10240  // 2*N + E*255 rounded up to 256
#define MAXT 40     // max 256-row M tiles across experts

typedef __attribute__((ext_vector_type(8))) short bf16x8;
typedef __attribute__((ext_vector_type(4))) float f32x4;

__device__ __forceinline__ float b2f(uint16_t u) {
  return __uint_as_float(((uint32_t)u) << 16);
}
__device__ __forceinline__ uint16_t f2b(float f) {
  uint32_t x = __float_as_uint(f);
  uint32_t r = (x + 0x7fffu + ((x >> 16) & 1u)) >> 16;
  return (uint16_t)r;
}

__device__ __forceinline__ void gl2lds16(const void* g, void* l) {
  __builtin_amdgcn_global_load_lds(
      (const __attribute__((address_space(1))) uint32_t*)g,
      (__attribute__((address_space(3))) uint32_t*)l, 16, 0, 0);
}

// ---- staging helpers (XOR-swizzled source, linear LDS dest) ----
// 256x64 bf16 tile (32 KB), 8 waves, 4 loads/wave (full) or 2 (half h).
__device__ __forceinline__ void stage256(const uint16_t* src, int ldK,
                                         char* lds, int wave, int lane) {
  int u = (lane & 7) ^ (lane >> 3);
  const char* s0 = (const char*)src + u * 16;
  size_t rb = (size_t)ldK * 2;
  int Rb = wave * 32 + (lane >> 3);
  char* d0 = lds + wave * 4096;
  for (int c = 0; c < 4; ++c)
    gl2lds16(s0 + (size_t)(Rb + c * 8) * rb, d0 + c * 1024);
}
__device__ __forceinline__ void stage256h(const uint16_t* src, int ldK,
                                          char* lds, int wave, int lane,
                                          int h) {
  int u = (lane & 7) ^ (lane >> 3);
  const char* s0 = (const char*)src + u * 16;
  size_t rb = (size_t)ldK * 2;
  int Rb = wave * 32 + (lane >> 3);
  char* d0 = lds + wave * 4096;
  for (int c = 2 * h; c < 2 * h + 2; ++c)
    gl2lds16(s0 + (size_t)(Rb + c * 8) * rb, d0 + c * 1024);
}
// 128x64 bf16 tile (16 KB), 8 waves, 2 loads/wave (full) or 1 (half h).
__device__ __forceinline__ void stage128(const uint16_t* src, int ldK,
                                         char* lds, int wave, int lane) {
  int u = (lane & 7) ^ (lane >> 3);
  const char* s0 = (const char*)src + u * 16;
  size_t rb = (size_t)ldK * 2;
  int Rb = wave * 16 + (lane >> 3);
  char* d0 = lds + wave * 2048;
  for (int c = 0; c < 2; ++c)
    gl2lds16(s0 + (size_t)(Rb + c * 8) * rb, d0 + c * 1024);
}
__device__ __forceinline__ void stage128h(const uint16_t* src, int ldK,
                                          char* lds, int wave, int lane,
                                          int h) {
  int u = (lane & 7) ^ (lane >> 3);
  const char* s0 = (const char*)src + u * 16;
  size_t rb = (size_t)ldK * 2;
  int Rb = wave * 16 + (lane >> 3);
  gl2lds16(s0 + (size_t)(Rb + h * 8) * rb, lds + wave * 2048 + h * 1024);
}

__device__ __forceinline__ bf16x8 read_frag(const char* lds, int R, int s,
                                            int q) {
  int unit = ((s << 2) + q) ^ (R & 7);
  return *(const bf16x8*)(lds + R * 128 + unit * 16);
}

// ---------------- input dtype detection ----------------
__global__ __launch_bounds__(256) void detect_kernel(
    const uint16_t* __restrict__ x, int* __restrict__ flag) {
  __shared__ int cnt;
  if (threadIdx.x == 0) cnt = 0;
  __syncthreads();
  int ok = 0;
  for (int j = 0; j < 16; ++j) {
    uint16_t u = x[threadIdx.x * 16 + j];
    int e = (u >> 7) & 0xff;
    ok += (u == 0 || (e >= 96 && e <= 143)) ? 1 : 0;
  }
  atomicAdd(&cnt, ok);
  __syncthreads();
  if (threadIdx.x == 0) *flag = (cnt >= 3700) ? 1 : 0;  // 1 = bf16 inputs
}

// ---------------- router: fp32 logits, top-2 (NO atomics) ----------
__global__ __launch_bounds__(256) void router_kernel(
    const void* __restrict__ xraw, const void* __restrict__ gwraw,
    const int* __restrict__ flag, void* __restrict__ dout,
    int* __restrict__ top_i, float* __restrict__ top_w) {
  int fl = *flag;
  int wave = threadIdx.x >> 6, lane = threadIdx.x & 63;
  int t = blockIdx.x * 4 + wave;  // one wave per token
  float xv[16];
  if (fl) {
    const uint16_t* xr = (const uint16_t*)xraw + (size_t)t * H_DIM + lane * 16;
    uint4 a = *(const uint4*)xr;
    uint4 b = *(const uint4*)(xr + 8);
    uint32_t w[8] = {a.x, a.y, a.z, a.w, b.x, b.y, b.z, b.w};
    for (int j = 0; j < 8; ++j) {
      xv[2 * j] = b2f((uint16_t)(w[j] & 0xffff));
      xv[2 * j + 1] = b2f((uint16_t)(w[j] >> 16));
    }
  } else {
    const float* xr = (const float*)xraw + (size_t)t * H_DIM + lane * 16;
    for (int j = 0; j < 4; ++j) {
      float4 v = ((const float4*)xr)[j];
      xv[4 * j] = v.x; xv[4 * j + 1] = v.y;
      xv[4 * j + 2] = v.z; xv[4 * j + 3] = v.w;
    }
  }
  float acc[E_NUM];
  for (int e = 0; e < E_NUM; ++e) {
    float s = 0.f;
    if (fl) {
      const uint16_t* gr =
          (const uint16_t*)gwraw + (size_t)e * H_DIM + lane * 16;
      uint4 a = *(const uint4*)gr;
      uint4 b = *(const uint4*)(gr + 8);
      uint32_t w[8] = {a.x, a.y, a.z, a.w, b.x, b.y, b.z, b.w};
      for (int j = 0; j < 8; ++j) {
        s += xv[2 * j] * b2f((uint16_t)(w[j] & 0xffff));
        s += xv[2 * j + 1] * b2f((uint16_t)(w[j] >> 16));
      }
    } else {
      const float* gr = (const float*)gwraw + (size_t)e * H_DIM + lane * 16;
      for (int j = 0; j < 4; ++j) {
        float4 v = ((const float4*)gr)[j];
        s += xv[4 * j] * v.x + xv[4 * j + 1] * v.y + xv[4 * j + 2] * v.z +
             xv[4 * j + 3] * v.w;
      }
    }
    acc[e] = s;
  }
  for (int off = 32; off >= 1; off >>= 1)
    for (int e = 0; e < E_NUM; ++e)
      acc[e] += __shfl_xor(acc[e], off, 64);
  if (lane < E_NUM) {
    size_t idx = (size_t)N_TOK * H_DIM + (size_t)t * E_NUM + lane;
    if (fl)
      ((uint16_t*)dout)[idx] = f2b(acc[lane]);
    else
      ((float*)dout)[idx] = acc[lane];
  }
  if (lane == 0) {
    int b0 = 0;
    float v0 = acc[0];
    for (int e = 1; e < E_NUM; ++e)
      if (acc[e] > v0) { v0 = acc[e]; b0 = e; }
    int b1 = (b0 == 0) ? 1 : 0;
    float v1 = acc[b1];
    for (int e = 0; e < E_NUM; ++e)
      if (e != b0 && acc[e] > v1) { v1 = acc[e]; b1 = e; }
    float w0 = 1.f / (1.f + expf(v1 - v0));  // top-2 renorm == 2-way softmax
    top_i[2 * t] = b0; top_i[2 * t + 1] = b1;
    top_w[2 * t] = w0; top_w[2 * t + 1] = 1.f - w0;
  }
}

// ------- histogram + scan + row assignment + 256-row tile map --------------
__global__ __launch_bounds__(1024) void histscan_kernel(
    const int* __restrict__ top_i, int* __restrict__ counts,
    int* __restrict__ bases, int* __restrict__ row_of,
    int* __restrict__ tile_e, int* __restrict__ tile_row,
    int* __restrict__ ntiles) {
  int tid = threadIdx.x;           // 0..1023
  int lane = tid & 63, wave = tid >> 6;  // 16 waves
  int e_loc[8];
  int c[E_NUM] = {};
  for (int j = 0; j < 8; ++j) {
    int idx = tid * 8 + j;
    int e = top_i[idx];
    e_loc[j] = e;
    c[e]++;
  }
  int inc[E_NUM];
  for (int k = 0; k < E_NUM; ++k) inc[k] = c[k];
  for (int off = 1; off < 64; off <<= 1) {
    for (int k = 0; k < E_NUM; ++k) {
      int v = __shfl_up(inc[k], off, 64);
      if (lane >= off) inc[k] += v;
    }
  }
  __shared__ int wtot[16][E_NUM];
  __shared__ int woff[16][E_NUM];
  __shared__ int base_s[E_NUM];
  if (lane == 63)
    for (int k = 0; k < E_NUM; ++k) wtot[wave][k] = inc[k];
  __syncthreads();
  if (tid < E_NUM) {  // thread k scans expert k across waves
    int run = 0;
    for (int w = 0; w < 16; ++w) {
      woff[w][tid] = run;
      run += wtot[w][tid];
    }
    counts[tid] = run;
    wtot[0][tid] = run;  // reuse as totals
  }
  __syncthreads();
  if (tid == 0) {
    int b = 0, nt = 0;
    for (int e = 0; e < E_NUM; ++e) {
      bases[e] = b;
      base_s[e] = b;
      int cc = wtot[0][e];
      int te = (cc + 255) >> 8;  // 256-row tiles
      for (int j = 0; j < te; ++j) {
        tile_e[nt] = e;
        tile_row[nt] = b + j * 256;
        ++nt;
      }
      b += te << 8;
    }
    *ntiles = nt;
  }
  __syncthreads();
  int run[E_NUM];
  for (int k = 0; k < E_NUM; ++k)
    run[k] = base_s[k] + woff[wave][k] + inc[k] - c[k];  // exclusive prefix
  for (int j = 0; j < 8; ++j) {
    int idx = tid * 8 + j;
    int r = run[e_loc[j]]++;
    row_of[idx] = r;
  }
}

// ---------------- gather tokens -> contiguous bf16 rows (no atomics) -------
__global__ __launch_bounds__(256) void gather_kernel(
    const void* __restrict__ xraw, const int* __restrict__ flag,
    const int* __restrict__ row_of, uint16_t* __restrict__ Xg) {
  int t = blockIdx.x;
  int rs0 = row_of[2 * t], rs1 = row_of[2 * t + 1];
  uint2 v;
  if (*flag) {
    v = ((const uint2*)((const uint16_t*)xraw + (size_t)t * H_DIM))[threadIdx.x];
  } else {
    float4 f =
        ((const float4*)((const float*)xraw + (size_t)t * H_DIM))[threadIdx.x];
    v.x = (uint32_t)f2b(f.x) | ((uint32_t)f2b(f.y) << 16);
    v.y = (uint32_t)f2b(f.z) | ((uint32_t)f2b(f.w) << 16);
  }
  ((uint2*)(Xg + (size_t)rs0 * H_DIM))[threadIdx.x] = v;
  ((uint2*)(Xg + (size_t)rs1 * H_DIM))[threadIdx.x] = v;
}

// ------------- weight transpose [E][K][N] -> [E][N][K], canonicalize bf16 ---
// Dual-source variant: z selects tensor (z<E: src0->dst0, else src1->dst1).
__global__ __launch_bounds__(256) void transpose_kernel(
    const void* __restrict__ W0, const void* __restrict__ W1,
    const int* __restrict__ flag, uint16_t* __restrict__ Wt0,
    uint16_t* __restrict__ Wt1, int K, int N) {
  int z = blockIdx.z;
  int e = z & (E_NUM - 1);
  const void* W = (z < E_NUM) ? W0 : W1;
  uint16_t* Wt = (z < E_NUM) ? Wt0 : Wt1;
  int n0 = blockIdx.x * 64, k0 = blockIdx.y * 64;
  __shared__ __align__(16) uint16_t tile[64][72];
  size_t ebase = (size_t)e * K * N;
  uint16_t* Wout = Wt + ebase;
  int fl = *flag;
  int r = threadIdx.x >> 3;
  int c = (threadIdx.x & 7) * 8;
  if (fl) {
    const uint16_t* Win = (const uint16_t*)W + ebase;
    for (int it = 0; it < 2; ++it) {
      int row = r + it * 32;
      uint4 v = *(const uint4*)(Win + (size_t)(k0 + row) * N + n0 + c);
      *(uint4*)&tile[row][c] = v;
    }
  } else {
    const float* Win = (const float*)W + ebase;
    for (int it = 0; it < 2; ++it) {
      int row = r + it * 32;
      const float* p = Win + (size_t)(k0 + row) * N + n0 + c;
      float4 a = ((const float4*)p)[0];
      float4 b = ((const float4*)p)[1];
      uint16_t* tp = &tile[row][c];
      tp[0] = f2b(a.x); tp[1] = f2b(a.y); tp[2] = f2b(a.z); tp[3] = f2b(a.w);
      tp[4] = f2b(b.x); tp[5] = f2b(b.y); tp[6] = f2b(b.z); tp[7] = f2b(b.w);
    }
  }
  __syncthreads();
  for (int it = 0; it < 2; ++it) {
    int n = r + it * 32;
    uint4 o;
    o.x = (uint32_t)tile[c + 0][n] | ((uint32_t)tile[c + 1][n] << 16);
    o.y = (uint32_t)tile[c + 2][n] | ((uint32_t)tile[c + 3][n] << 16);
    o.z = (uint32_t)tile[c + 4][n] | ((uint32_t)tile[c + 5][n] << 16);
    o.w = (uint32_t)tile[c + 6][n] | ((uint32_t)tile[c + 7][n] << 16);
    *(uint4*)(Wout + (size_t)(n0 + n) * K + k0 + c) = o;
  }
}

// ------------- fused up+gate GEMM, 4-phase interleaved K-loop --------------
// BM=256, BN=128 per tensor, BK=64, 8 waves (4M x 2N, 64x64 wave tiles).
// Per K-tile: 4 phases, each {2 G-loads of next tile | ds_reads | 16 MFMA}
// with ONE counted vmcnt per tile (p1) and raw barriers.
__global__ __launch_bounds__(512, 2) void gemm_upgate(
    const uint16_t* __restrict__ Xg,
    const uint16_t* __restrict__ WtU, const uint16_t* __restrict__ WtG,
    const void* __restrict__ buRaw, const void* __restrict__ bgRaw,
    const int* __restrict__ flag, const int* __restrict__ tile_e,
    const int* __restrict__ tile_row, const int* __restrict__ ntiles,
    uint16_t* __restrict__ phi) {
  int ty = blockIdx.y;
  if (ty >= *ntiles) return;
  int e = tile_e[ty];
  int r0 = tile_row[ty];
  int n0 = blockIdx.x * 128;
  const uint16_t* A = Xg + (size_t)r0 * H_DIM;
  const uint16_t* BU = WtU + (size_t)e * F_DIM * H_DIM + (size_t)n0 * H_DIM;
  const uint16_t* BG = WtG + (size_t)e * F_DIM * H_DIM + (size_t)n0 * H_DIM;

  __shared__ __align__(16) char lA[2][256 * 128];   // 64 KB
  __shared__ __align__(16) char lBu[2][128 * 128];  // 32 KB
  __shared__ __align__(16) char lBg[2][128 * 128];  // 32 KB

  int tid = threadIdx.x;
  int wave = tid >> 6, lane = tid & 63;
  int wm = wave >> 1, wn = wave & 1;
  int q = lane >> 4, mr = lane & 15;

  f32x4 accU[4][4] = {};
  f32x4 accG[4][4] = {};

  // prologue: tile 0 (8 loads/wave)
  stage256(A, H_DIM, lA[0], wave, lane);
  stage128(BU, H_DIM, lBu[0], wave, lane);
  stage128(BG, H_DIM, lBg[0], wave, lane);

  const int NT = H_DIM / 64;  // 16
  for (int t = 0; t < NT; ++t) {
    int cur = t & 1, nxt = cur ^ 1;
    int k1 = (t + 1) * 64;
    bool more = (t + 1 < NT);
    const char* pA = lA[cur];
    const char* pU = lBu[cur];
    const char* pG = lBg[cur];

    // ---------- phase 1: U on mt{0,1} ----------
    if (more) {
      stage256h(A + k1, H_DIM, lA[nxt], wave, lane, 0);  // 2 loads
      asm volatile("s_waitcnt vmcnt(2)" ::: "memory");   // tile t landed
    } else {
      asm volatile("s_waitcnt vmcnt(0)" ::: "memory");
    }
    __builtin_amdgcn_s_barrier();
    __builtin_amdgcn_sched_barrier(0);
    bf16x8 af0[2][2], bu[4][2];
#pragma unroll
    for (int mt = 0; mt < 2; ++mt)
#pragma unroll
      for (int s = 0; s < 2; ++s)
        af0[mt][s] = read_frag(pA, wm * 64 + mt * 16 + mr, s, q);
#pragma unroll
    for (int nt = 0; nt < 4; ++nt)
#pragma unroll
      for (int s = 0; s < 2; ++s)
        bu[nt][s] = read_frag(pU, wn * 64 + nt * 16 + mr, s, q);
    asm volatile("s_waitcnt lgkmcnt(0)" ::: "memory");
    __builtin_amdgcn_sched_barrier(0);
    __builtin_amdgcn_s_setprio(1);
#pragma unroll
    for (int mt = 0; mt < 2; ++mt)
#pragma unroll
      for (int nt = 0; nt < 4; ++nt) {
        accU[mt][nt] = __builtin_amdgcn_mfma_f32_16x16x32_bf16(
            af0[mt][0], bu[nt][0], accU[mt][nt], 0, 0, 0);
        accU[mt][nt] = __builtin_amdgcn_mfma_f32_16x16x32_bf16(
            af0[mt][1], bu[nt][1], accU[mt][nt], 0, 0, 0);
      }
    __builtin_amdgcn_s_setprio(0);
    __builtin_amdgcn_sched_barrier(0);
    __builtin_amdgcn_s_barrier();

    // ---------- phase 2: G on mt{0,1} (af0 reused) ----------
    if (more) stage256h(A + k1, H_DIM, lA[nxt], wave, lane, 1);  // 2 loads
    bf16x8 bg[4][2];
#pragma unroll
    for (int nt = 0; nt < 4; ++nt)
#pragma unroll
      for (int s = 0; s < 2; ++s)
        bg[nt][s] = read_frag(pG, wn * 64 + nt * 16 + mr, s, q);
    asm volatile("s_waitcnt lgkmcnt(0)" ::: "memory");
    __builtin_amdgcn_sched_barrier(0);
    __builtin_amdgcn_s_setprio(1);
#pragma unroll
    for (int mt = 0; mt < 2; ++mt)
#pragma unroll
      for (int nt = 0; nt < 4; ++nt) {
        accG[mt][nt] = __builtin_amdgcn_mfma_f32_16x16x32_bf16(
            af0[mt][0], bg[nt][0], accG[mt][nt], 0, 0, 0);
        accG[mt][nt] = __builtin_amdgcn_mfma_f32_16x16x32_bf16(
            af0[mt][1], bg[nt][1], accG[mt][nt], 0, 0, 0);
      }
    __builtin_amdgcn_s_setprio(0);
    __builtin_amdgcn_sched_barrier(0);
    __builtin_amdgcn_s_barrier();

    // ---------- phase 3: U on mt{2,3} ----------
    if (more) stage128(BU + k1, H_DIM, lBu[nxt], wave, lane);  // 2 loads
    bf16x8 af1[2][2], bu2[4][2];
#pragma unroll
    for (int mt = 0; mt < 2; ++mt)
#pragma unroll
      for (int s = 0; s < 2; ++s)
        af1[mt][s] = read_frag(pA, wm * 64 + (mt + 2) * 16 + mr, s, q);
#pragma unroll
    for (int nt = 0; nt < 4; ++nt)
#pragma unroll
      for (int s = 0; s < 2; ++s)
        bu2[nt][s] = read_frag(pU, wn * 64 + nt * 16 + mr, s, q);
    asm volatile("s_waitcnt lgkmcnt(0)" ::: "memory");
    __builtin_amdgcn_sched_barrier(0);
    __builtin_amdgcn_s_setprio(1);
#pragma unroll
    for (int mt = 0; mt < 2; ++mt)
#pragma unroll
      for (int nt = 0; nt < 4; ++nt) {
        accU[mt + 2][nt] = __builtin_amdgcn_mfma_f32_16x16x32_bf16(
            af1[mt][0], bu2[nt][0], accU[mt + 2][nt], 0, 0, 0);
        accU[mt + 2][nt] = __builtin_amdgcn_mfma_f32_16x16x32_bf16(
            af1[mt][1], bu2[nt][1], accU[mt + 2][nt], 0, 0, 0);
      }
    __builtin_amdgcn_s_setprio(0);
    __builtin_amdgcn_sched_barrier(0);
    __builtin_amdgcn_s_barrier();

    // ---------- phase 4: G on mt{2,3} (af1 reused) ----------
    if (more) stage128(BG + k1, H_DIM, lBg[nxt], wave, lane);  // 2 loads
    bf16x8 bg2[4][2];
#pragma unroll
    for (int nt = 0; nt < 4; ++nt)
#pragma unroll
      for (int s = 0; s < 2; ++s)
        bg2[nt][s] = read_frag(pG, wn * 64 + nt * 16 + mr, s, q);
    asm volatile("s_waitcnt lgkmcnt(0)" ::: "memory");
    __builtin_amdgcn_sched_barrier(0);
    __builtin_amdgcn_s_setprio(1);
#pragma unroll
    for (int mt = 0; mt < 2; ++mt)
#pragma unroll
      for (int nt = 0; nt < 4; ++nt) {
        accG[mt + 2][nt] = __builtin_amdgcn_mfma_f32_16x16x32_bf16(
            af1[mt][0], bg2[nt][0], accG[mt + 2][nt], 0, 0, 0);
        accG[mt + 2][nt] = __builtin_amdgcn_mfma_f32_16x16x32_bf16(
            af1[mt][1], bg2[nt][1], accG[mt + 2][nt], 0, 0, 0);
      }
    __builtin_amdgcn_s_setprio(0);
    __builtin_amdgcn_sched_barrier(0);
    __builtin_amdgcn_s_barrier();
  }

  int fl = *flag;
  int rb_ = r0 + wm * 64;
  int cb_ = n0 + wn * 64;
  for (int nt = 0; nt < 4; ++nt) {
    int col = cb_ + nt * 16 + mr;
    float bu_v, bg_v;
    if (fl) {
      bu_v = b2f(((const uint16_t*)buRaw)[(size_t)e * F_DIM + col]);
      bg_v = b2f(((const uint16_t*)bgRaw)[(size_t)e * F_DIM + col]);
    } else {
      bu_v = ((const float*)buRaw)[(size_t)e * F_DIM + col];
      bg_v = ((const float*)bgRaw)[(size_t)e * F_DIM + col];
    }
    for (int mt = 0; mt < 4; ++mt) {
      int r = rb_ + mt * 16 + q * 4;
      for (int rg = 0; rg < 4; ++rg) {
        float u = accU[mt][nt][rg] + bu_v;
        float v = accG[mt][nt][rg] + bg_v;
        float s = v / (1.f + expf(-v));  // silu
        phi[(size_t)(r + rg) * F_DIM + col] = f2b(s * u);
      }
    }
  }
}

// ------------- down GEMM, 2-phase interleaved K-loop (no atomics) ----------
// BM=256, BN=128, BK=64, 8 waves (4M x 2N). Grid: x=tile (fast) so
// consecutive blocks share the same B-slab (per-XCD L2 locality).
__global__ __launch_bounds__(512, 2) void gemm_down(
    const uint16_t* __restrict__ phi, const uint16_t* __restrict__ WtD,
    const void* __restrict__ bdRaw, const int* __restrict__ flag,
    const int* __restrict__ tile_e, const int* __restrict__ tile_row,
    const int* __restrict__ ntiles, float* __restrict__ Yrows) {
  int ty = blockIdx.x;
  if (ty >= *ntiles) return;
  int e = tile_e[ty];
  int r0 = tile_row[ty];
  int n0 = blockIdx.y * 128;
  const uint16_t* A = phi + (size_t)r0 * F_DIM;
  const uint16_t* B = WtD + (size_t)e * H_DIM * F_DIM + (size_t)n0 * F_DIM;

  __shared__ __align__(16) char lA[2][256 * 128];  // 64 KB
  __shared__ __align__(16) char lB[2][128 * 128];  // 32 KB

  int tid = threadIdx.x;
  int wave = tid >> 6, lane = tid & 63;
  int wm = wave >> 1, wn = wave & 1;
  int q = lane >> 4, mr = lane & 15;

  f32x4 acc[4][4] = {};

  stage256(A, F_DIM, lA[0], wave, lane);  // 4 loads
  stage128(B, F_DIM, lB[0], wave, lane);  // 2 loads

  const int NT = F_DIM / 64;  // 32
  for (int t = 0; t < NT; ++t) {
    int cur = t & 1, nxt = cur ^ 1;
    int k1 = (t + 1) * 64;
    bool more = (t + 1 < NT);
    const char* pA = lA[cur];
    const char* pB = lB[cur];

    // ---------- phase 1: mt{0,1} ----------
    if (more) {
      stage256h(A + k1, F_DIM, lA[nxt], wave, lane, 0);  // 2
      stage128h(B + k1, F_DIM, lB[nxt], wave, lane, 0);  // 1
      asm volatile("s_waitcnt vmcnt(3)" ::: "memory");
    } else {
      asm volatile("s_waitcnt vmcnt(0)" ::: "memory");
    }
    __builtin_amdgcn_s_barrier();
    __builtin_amdgcn_sched_barrier(0);
    bf16x8 af[2][2], bf[4][2];
#pragma unroll
    for (int mt = 0; mt < 2; ++mt)
#pragma unroll
      for (int s = 0; s < 2; ++s)
        af[mt][s] = read_frag(pA, wm * 64 + mt * 16 + mr, s, q);
#pragma unroll
    for (int nt = 0; nt < 4; ++nt)
#pragma unroll
      for (int s = 0; s < 2; ++s)
        bf[nt][s] = read_frag(pB, wn * 64 + nt * 16 + mr, s, q);
    asm volatile("s_waitcnt lgkmcnt(0)" ::: "memory");
    __builtin_amdgcn_sched_barrier(0);
    __builtin_amdgcn_s_setprio(1);
#pragma unroll
    for (int mt = 0; mt < 2; ++mt)
#pragma unroll
      for (int nt = 0; nt < 4; ++nt) {
        acc[mt][nt] = __builtin_amdgcn_mfma_f32_16x16x32_bf16(
            af[mt][0], bf[nt][0], acc[mt][nt], 0, 0, 0);
        acc[mt][nt] = __builtin_amdgcn_mfma_f32_16x16x32_bf16(
            af[mt][1], bf[nt][1], acc[mt][nt], 0, 0, 0);
      }
    __builtin_amdgcn_s_setprio(0);
    __builtin_amdgcn_sched_barrier(0);
    __builtin_amdgcn_s_barrier();

    // ---------- phase 2: mt{2,3} ----------
    if (more) {
      stage256h(A + k1, F_DIM, lA[nxt], wave, lane, 1);  // 2
      stage128h(B + k1, F_DIM, lB[nxt], wave, lane, 1);  // 1
    }
    bf16x8 af2[2][2], bf2[4][2];
#pragma unroll
    for (int mt = 0; mt < 2; ++mt)
#pragma unroll
      for (int s = 0; s < 2; ++s)
        af2[mt][s] = read_frag(pA, wm * 64 + (mt + 2) * 16 + mr, s, q);
#pragma unroll
    for (int nt = 0; nt < 4; ++nt)
#pragma unroll
      for (int s = 0; s < 2; ++s)
        bf2[nt][s] = read_frag(pB, wn * 64 + nt * 16 + mr, s, q);
    asm volatile("s_waitcnt lgkmcnt(0)" ::: "memory");
    __builtin_amdgcn_sched_barrier(0);
    __builtin_amdgcn_s_setprio(1);
#pragma unroll
    for (int mt = 0; mt < 2; ++mt)
#pragma unroll
      for (int nt = 0; nt < 4; ++nt) {
        acc[mt + 2][nt] = __builtin_amdgcn_mfma_f32_16x16x32_bf16(
            af2[mt][0], bf2[nt][0], acc[mt + 2][nt], 0, 0, 0);
        acc[mt + 2][nt] = __builtin_amdgcn_mfma_f32_16x16x32_bf16(
            af2[mt][1], bf2[nt][1], acc[mt + 2][nt], 0, 0, 0);
      }
    __builtin_amdgcn_s_setprio(0);
    __builtin_amdgcn_sched_barrier(0);
    __builtin_amdgcn_s_barrier();
  }

  int fl = *flag;
  int rb_ = r0 + wm * 64;
  int cb_ = n0 + wn * 64;
  for (int nt = 0; nt < 4; ++nt) {
    int col = cb_ + nt * 16 + mr;
    float bd_v = fl ? b2f(((const uint16_t*)bdRaw)[(size_t)e * H_DIM + col])
                    : ((const float*)bdRaw)[(size_t)e * H_DIM + col];
    for (int mt = 0; mt < 4; ++mt) {
      int r = rb_ + mt * 16 + q * 4;
      for (int rg = 0; rg < 4; ++rg)
        Yrows[(size_t)(r + rg) * H_DIM + col] = acc[mt][nt][rg] + bd_v;
    }
  }
}

// ---------------- combine: out[t] = w0*Y[r0] + w1*Y[r1] ---------------------
__global__ __launch_bounds__(256) void combine_kernel(
    const float* __restrict__ Y, const int* __restrict__ row_of,
    const float* __restrict__ top_w, const int* __restrict__ flag,
    void* __restrict__ out) {
  int t = blockIdx.x;
  int r0 = row_of[2 * t], r1 = row_of[2 * t + 1];
  float w0 = top_w[2 * t], w1 = top_w[2 * t + 1];
  int i = threadIdx.x;
  float4 a = ((const float4*)(Y + (size_t)r0 * H_DIM))[i];
  float4 b = ((const float4*)(Y + (size_t)r1 * H_DIM))[i];
  float4 o;
  o.x = w0 * a.x + w1 * b.x;
  o.y = w0 * a.y + w1 * b.y;
  o.z = w0 * a.z + w1 * b.z;
  o.w = w0 * a.w + w1 * b.w;
  if (*flag) {
    uint2 p;
    p.x = (uint32_t)f2b(o.x) | ((uint32_t)f2b(o.y) << 16);
    p.y = (uint32_t)f2b(o.z) | ((uint32_t)f2b(o.w) << 16);
    ((uint2*)out)[(size_t)t * 256 + i] = p;
  } else {
    ((float4*)out)[(size_t)t * 256 + i] = o;
  }
}

extern "C" void kernel_launch(void* const* d_in, const int* in_sizes, int n_in,
                              void* d_out, int out_size, void* d_ws, size_t ws_size,
                              hipStream_t stream) {
  const void* x = d_in[0];
  const void* gw = d_in[1];
  const void* w_up = d_in[2];
  const void* w_gate = d_in[3];
  const void* w_down = d_in[4];
  const void* b_up = d_in[5];
  const void* b_gate = d_in[6];
  const void* b_down = d_in[7];

  char* ws = (char*)d_ws;
  size_t off = 0;
  auto alloc = [&](size_t bytes) -> void* {
    void* p = ws + off;
    off += (bytes + 255) & ~(size_t)255;
    return p;
  };
  int* counts = (int*)alloc(32);
  int* bases = (int*)alloc(32);
  int* flag = (int*)alloc(32);
  int* ntiles = (int*)alloc(32);
  int* tile_e = (int*)alloc(sizeof(int) * MAXT);
  int* tile_row = (int*)alloc(sizeof(int) * MAXT);
  int* top_i = (int*)alloc(sizeof(int) * N_TOK * 2);
  float* top_w = (float*)alloc(sizeof(float) * N_TOK * 2);
  int* row_of = (int*)alloc(sizeof(int) * N_TOK * 2);
  uint16_t* Xg = (uint16_t*)alloc((size_t)RCAP * H_DIM * 2);
  uint16_t* phi = (uint16_t*)alloc((size_t)RCAP * F_DIM * 2);
  uint16_t* WtU = (uint16_t*)alloc((size_t)E_NUM * H_DIM * F_DIM * 2);
  uint16_t* WtG = (uint16_t*)alloc((size_t)E_NUM * H_DIM * F_DIM * 2);
  float* Yrows = (float*)alloc((size_t)RCAP * H_DIM * sizeof(float));

  detect_kernel<<<1, 256, 0, stream>>>((const uint16_t*)x, flag);
  router_kernel<<<N_TOK / 4, 256, 0, stream>>>(x, gw, flag, d_out, top_i,
                                               top_w);
  histscan_kernel<<<1, 1024, 0, stream>>>(top_i, counts, bases, row_of,
                                          tile_e, tile_row, ntiles);
  gather_kernel<<<N_TOK, 256, 0, stream>>>(x, flag, row_of, Xg);

  // up + gate transposes fused into one launch (z<8: up, z>=8: gate)
  transpose_kernel<<<dim3(F_DIM / 64, H_DIM / 64, 2 * E_NUM), 256, 0,
                     stream>>>(w_up, w_gate, flag, WtU, WtG, H_DIM, F_DIM);

  gemm_upgate<<<dim3(F_DIM / 128, MAXT), 512, 0, stream>>>(
      Xg, WtU, WtG, b_up, b_gate, flag, tile_e, tile_row, ntiles, phi);

  // down transpose reuses WtU buffer (WtG unused from here on)
  transpose_kernel<<<dim3(H_DIM / 64, F_DIM / 64, E_NUM), 256, 0, stream>>>(
      w_down, w_down, flag, WtU, WtU, F_DIM, H_DIM);
  gemm_down<<<dim3(MAXT, H_DIM / 128), 512, 0, stream>>>(
      phi, WtU, b_down, flag, tile_e, tile_row, ntiles, Yrows);

  combine_kernel<<<N_TOK, 256, 0, stream>>>(Yrows, row_of, top_w, flag, d_out);
}

// Round 6
// 403.604 us; speedup vs baseline: 1.2798x; 1.2798x over previous
//
#include <hip/hip_runtime.h>
#include <hip/hip_bf16.h>
#include <cstdint>
#include <cstddef>

// B=2,S=2048 -> N=4096 tokens, H=1024, F=2048, E=8, top-2 routing.
// R12: occupancy via register relief (not launch_bounds decree).
// gemm_upgate: BM=128, BN=64 per tensor (acc 64 f32/thread, LDS 32KB,
// ~1088 blocks, 3 blocks/CU without spills). Each wave owns 32 rows x both
// tensors -> silu epilogue wave-local, A-frags shared across U/G MFMAs.
// gemm_down: R9 geometry + __launch_bounds__(256,3) (fits 170-reg budget).
// Rest identical to R9 (best measured: 417us).
#define N_TOK 4096
#define H_DIM 1024
#define F_DIM 2048
#define E_NUM 8
#define RCAP 9216  // 2*N + E*127 rounded to 128
#define MAXT 80    // max 128-row M tiles across experts

typedef __attribute__((ext_vector_type(8))) short bf16x8;
typedef __attribute__((ext_vector_type(4))) float f32x4;

__device__ __forceinline__ float b2f(uint16_t u) {
  return __uint_as_float(((uint32_t)u) << 16);
}
__device__ __forceinline__ uint16_t f2b(float f) {
  uint32_t x = __float_as_uint(f);
  uint32_t r = (x + 0x7fffu + ((x >> 16) & 1u)) >> 16;
  return (uint16_t)r;
}

__device__ __forceinline__ void gl2lds16(const void* g, void* l) {
  __builtin_amdgcn_global_load_lds(
      (const __attribute__((address_space(1))) uint32_t*)g,
      (__attribute__((address_space(3))) uint32_t*)l, 16, 0, 0);
}

// Stage a 128x64 bf16 tile (16 KB) into LDS with XOR-swizzled 16B units.
// 4 waves, 4 global_load_lds each.
__device__ __forceinline__ void stage_tile(const uint16_t* src, int ldK,
                                           char* lds, int wave, int lane) {
  int u = (lane & 7) ^ (lane >> 3);
  const char* s0 = (const char*)src + u * 16;
  size_t rb = (size_t)ldK * 2;
  int Rb = wave * 32 + (lane >> 3);
  for (int c = 0; c < 4; ++c) {
    gl2lds16(s0 + (size_t)(Rb + c * 8) * rb, lds + wave * 4096 + c * 1024);
  }
}

// Stage a 64x64 bf16 tile (8 KB) into LDS, 4 waves, 2 loads each.
// Same row-slot/swizzle layout as stage_tile ((row&7) == lane>>3 here too).
__device__ __forceinline__ void stage64(const uint16_t* src, int ldK,
                                        char* lds, int wave, int lane) {
  int u = (lane & 7) ^ (lane >> 3);
  const char* s0 = (const char*)src + u * 16;
  size_t rb = (size_t)ldK * 2;
  int Rb = wave * 16 + (lane >> 3);
  for (int c = 0; c < 2; ++c) {
    gl2lds16(s0 + (size_t)(Rb + c * 8) * rb, lds + wave * 2048 + c * 1024);
  }
}

__device__ __forceinline__ bf16x8 read_frag(const char* lds, int R, int s,
                                            int q) {
  int unit = ((s << 2) + q) ^ (R & 7);
  return *(const bf16x8*)(lds + R * 128 + unit * 16);
}

// ---------------- input dtype detection ----------------
__global__ __launch_bounds__(256) void detect_kernel(
    const uint16_t* __restrict__ x, int* __restrict__ flag) {
  __shared__ int cnt;
  if (threadIdx.x == 0) cnt = 0;
  __syncthreads();
  int ok = 0;
  for (int j = 0; j < 16; ++j) {
    uint16_t u = x[threadIdx.x * 16 + j];
    int e = (u >> 7) & 0xff;
    ok += (u == 0 || (e >= 96 && e <= 143)) ? 1 : 0;
  }
  atomicAdd(&cnt, ok);
  __syncthreads();
  if (threadIdx.x == 0) *flag = (cnt >= 3700) ? 1 : 0;  // 1 = bf16 inputs
}

// ---------------- router: fp32 logits, top-2 (NO atomics) ----------
__global__ __launch_bounds__(256) void router_kernel(
    const void* __restrict__ xraw, const void* __restrict__ gwraw,
    const int* __restrict__ flag, void* __restrict__ dout,
    int* __restrict__ top_i, float* __restrict__ top_w) {
  int fl = *flag;
  int wave = threadIdx.x >> 6, lane = threadIdx.x & 63;
  int t = blockIdx.x * 4 + wave;  // one wave per token
  float xv[16];
  if (fl) {
    const uint16_t* xr = (const uint16_t*)xraw + (size_t)t * H_DIM + lane * 16;
    uint4 a = *(const uint4*)xr;
    uint4 b = *(const uint4*)(xr + 8);
    uint32_t w[8] = {a.x, a.y, a.z, a.w, b.x, b.y, b.z, b.w};
    for (int j = 0; j < 8; ++j) {
      xv[2 * j] = b2f((uint16_t)(w[j] & 0xffff));
      xv[2 * j + 1] = b2f((uint16_t)(w[j] >> 16));
    }
  } else {
    const float* xr = (const float*)xraw + (size_t)t * H_DIM + lane * 16;
    for (int j = 0; j < 4; ++j) {
      float4 v = ((const float4*)xr)[j];
      xv[4 * j] = v.x; xv[4 * j + 1] = v.y;
      xv[4 * j + 2] = v.z; xv[4 * j + 3] = v.w;
    }
  }
  float acc[E_NUM];
  for (int e = 0; e < E_NUM; ++e) {
    float s = 0.f;
    if (fl) {
      const uint16_t* gr =
          (const uint16_t*)gwraw + (size_t)e * H_DIM + lane * 16;
      uint4 a = *(const uint4*)gr;
      uint4 b = *(const uint4*)(gr + 8);
      uint32_t w[8] = {a.x, a.y, a.z, a.w, b.x, b.y, b.z, b.w};
      for (int j = 0; j < 8; ++j) {
        s += xv[2 * j] * b2f((uint16_t)(w[j] & 0xffff));
        s += xv[2 * j + 1] * b2f((uint16_t)(w[j] >> 16));
      }
    } else {
      const float* gr = (const float*)gwraw + (size_t)e * H_DIM + lane * 16;
      for (int j = 0; j < 4; ++j) {
        float4 v = ((const float4*)gr)[j];
        s += xv[4 * j] * v.x + xv[4 * j + 1] * v.y + xv[4 * j + 2] * v.z +
             xv[4 * j + 3] * v.w;
      }
    }
    acc[e] = s;
  }
  for (int off = 32; off >= 1; off >>= 1)
    for (int e = 0; e < E_NUM; ++e)
      acc[e] += __shfl_xor(acc[e], off, 64);
  if (lane < E_NUM) {
    size_t idx = (size_t)N_TOK * H_DIM + (size_t)t * E_NUM + lane;
    if (fl)
      ((uint16_t*)dout)[idx] = f2b(acc[lane]);
    else
      ((float*)dout)[idx] = acc[lane];
  }
  if (lane == 0) {
    int b0 = 0;
    float v0 = acc[0];
    for (int e = 1; e < E_NUM; ++e)
      if (acc[e] > v0) { v0 = acc[e]; b0 = e; }
    int b1 = (b0 == 0) ? 1 : 0;
    float v1 = acc[b1];
    for (int e = 0; e < E_NUM; ++e)
      if (e != b0 && acc[e] > v1) { v1 = acc[e]; b1 = e; }
    float w0 = 1.f / (1.f + expf(v1 - v0));  // top-2 renorm == 2-way softmax
    top_i[2 * t] = b0; top_i[2 * t + 1] = b1;
    top_w[2 * t] = w0; top_w[2 * t + 1] = 1.f - w0;
  }
}

// ------- histogram + scan + row assignment + 128-row tile map --------------
__global__ __launch_bounds__(1024) void histscan_kernel(
    const int* __restrict__ top_i, int* __restrict__ counts,
    int* __restrict__ bases, int* __restrict__ row_of,
    int* __restrict__ tile_e, int* __restrict__ tile_row,
    int* __restrict__ ntiles) {
  int tid = threadIdx.x;           // 0..1023
  int lane = tid & 63, wave = tid >> 6;  // 16 waves
  int e_loc[8];
  int c[E_NUM] = {};
  for (int j = 0; j < 8; ++j) {
    int idx = tid * 8 + j;
    int e = top_i[idx];
    e_loc[j] = e;
    c[e]++;
  }
  int inc[E_NUM];
  for (int k = 0; k < E_NUM; ++k) inc[k] = c[k];
  for (int off = 1; off < 64; off <<= 1) {
    for (int k = 0; k < E_NUM; ++k) {
      int v = __shfl_up(inc[k], off, 64);
      if (lane >= off) inc[k] += v;
    }
  }
  __shared__ int wtot[16][E_NUM];
  __shared__ int woff[16][E_NUM];
  __shared__ int base_s[E_NUM];
  if (lane == 63)
    for (int k = 0; k < E_NUM; ++k) wtot[wave][k] = inc[k];
  __syncthreads();
  if (tid < E_NUM) {  // thread k scans expert k across waves
    int run = 0;
    for (int w = 0; w < 16; ++w) {
      woff[w][tid] = run;
      run += wtot[w][tid];
    }
    counts[tid] = run;
    wtot[0][tid] = run;  // reuse as totals
  }
  __syncthreads();
  if (tid == 0) {
    int b = 0, nt = 0;
    for (int e = 0; e < E_NUM; ++e) {
      bases[e] = b;
      base_s[e] = b;
      int cc = wtot[0][e];
      int te = (cc + 127) >> 7;  // 128-row tiles
      for (int j = 0; j < te; ++j) {
        tile_e[nt] = e;
        tile_row[nt] = b + j * 128;
        ++nt;
      }
      b += te << 7;
    }
    *ntiles = nt;
  }
  __syncthreads();
  int run[E_NUM];
  for (int k = 0; k < E_NUM; ++k)
    run[k] = base_s[k] + woff[wave][k] + inc[k] - c[k];  // exclusive prefix
  for (int j = 0; j < 8; ++j) {
    int idx = tid * 8 + j;
    int r = run[e_loc[j]]++;
    row_of[idx] = r;
  }
}

// ---------------- gather tokens -> contiguous bf16 rows (no atomics) -------
__global__ __launch_bounds__(256) void gather_kernel(
    const void* __restrict__ xraw, const int* __restrict__ flag,
    const int* __restrict__ row_of, uint16_t* __restrict__ Xg) {
  int t = blockIdx.x;
  int rs0 = row_of[2 * t], rs1 = row_of[2 * t + 1];
  uint2 v;
  if (*flag) {
    v = ((const uint2*)((const uint16_t*)xraw + (size_t)t * H_DIM))[threadIdx.x];
  } else {
    float4 f =
        ((const float4*)((const float*)xraw + (size_t)t * H_DIM))[threadIdx.x];
    v.x = (uint32_t)f2b(f.x) | ((uint32_t)f2b(f.y) << 16);
    v.y = (uint32_t)f2b(f.z) | ((uint32_t)f2b(f.w) << 16);
  }
  ((uint2*)(Xg + (size_t)rs0 * H_DIM))[threadIdx.x] = v;
  ((uint2*)(Xg + (size_t)rs1 * H_DIM))[threadIdx.x] = v;
}

// ------------- weight transpose [E][K][N] -> [E][N][K], canonicalize bf16 ---
// Dual-source variant: z selects tensor (z<E: src0->dst0, else src1->dst1).
__global__ __launch_bounds__(256) void transpose_kernel(
    const void* __restrict__ W0, const void* __restrict__ W1,
    const int* __restrict__ flag, uint16_t* __restrict__ Wt0,
    uint16_t* __restrict__ Wt1, int K, int N) {
  int z = blockIdx.z;
  int e = z & (E_NUM - 1);
  const void* W = (z < E_NUM) ? W0 : W1;
  uint16_t* Wt = (z < E_NUM) ? Wt0 : Wt1;
  int n0 = blockIdx.x * 64, k0 = blockIdx.y * 64;
  __shared__ __align__(16) uint16_t tile[64][72];
  size_t ebase = (size_t)e * K * N;
  uint16_t* Wout = Wt + ebase;
  int fl = *flag;
  int r = threadIdx.x >> 3;
  int c = (threadIdx.x & 7) * 8;
  if (fl) {
    const uint16_t* Win = (const uint16_t*)W + ebase;
    for (int it = 0; it < 2; ++it) {
      int row = r + it * 32;
      uint4 v = *(const uint4*)(Win + (size_t)(k0 + row) * N + n0 + c);
      *(uint4*)&tile[row][c] = v;
    }
  } else {
    const float* Win = (const float*)W + ebase;
    for (int it = 0; it < 2; ++it) {
      int row = r + it * 32;
      const float* p = Win + (size_t)(k0 + row) * N + n0 + c;
      float4 a = ((const float4*)p)[0];
      float4 b = ((const float4*)p)[1];
      uint16_t* tp = &tile[row][c];
      tp[0] = f2b(a.x); tp[1] = f2b(a.y); tp[2] = f2b(a.z); tp[3] = f2b(a.w);
      tp[4] = f2b(b.x); tp[5] = f2b(b.y); tp[6] = f2b(b.z); tp[7] = f2b(b.w);
    }
  }
  __syncthreads();
  for (int it = 0; it < 2; ++it) {
    int n = r + it * 32;
    uint4 o;
    o.x = (uint32_t)tile[c + 0][n] | ((uint32_t)tile[c + 1][n] << 16);
    o.y = (uint32_t)tile[c + 2][n] | ((uint32_t)tile[c + 3][n] << 16);
    o.z = (uint32_t)tile[c + 4][n] | ((uint32_t)tile[c + 5][n] << 16);
    o.w = (uint32_t)tile[c + 6][n] | ((uint32_t)tile[c + 7][n] << 16);
    *(uint4*)(Wout + (size_t)(n0 + n) * K + k0 + c) = o;
  }
}

// ------------- fused up+gate GEMM: phi = silu(X@Wg+bg) * (X@Wu+bu) ---------
// BM=128, BN=64 per tensor, BK=64. 4 waves; wave w owns rows [w*32,w*32+32)
// x all 64 cols of BOTH tensors (silu wave-local, A-frags shared).
// acc = 64 f32/thread, LDS = 32 KB -> 3 blocks/CU at (256,3), no spills.
__global__ __launch_bounds__(256, 3) void gemm_upgate(
    const uint16_t* __restrict__ Xg,
    const uint16_t* __restrict__ WtU, const uint16_t* __restrict__ WtG,
    const void* __restrict__ buRaw, const void* __restrict__ bgRaw,
    const int* __restrict__ flag, const int* __restrict__ tile_e,
    const int* __restrict__ tile_row, const int* __restrict__ ntiles,
    uint16_t* __restrict__ phi) {
  int ty = blockIdx.y;
  if (ty >= *ntiles) return;
  int e = tile_e[ty];
  int r0 = tile_row[ty];
  int n0 = blockIdx.x * 64;
  const uint16_t* A = Xg + (size_t)r0 * H_DIM;
  const uint16_t* BU = WtU + (size_t)e * F_DIM * H_DIM + (size_t)n0 * H_DIM;
  const uint16_t* BG = WtG + (size_t)e * F_DIM * H_DIM + (size_t)n0 * H_DIM;

  __shared__ __align__(16) char lA[128 * 128];  // 16 KB
  __shared__ __align__(16) char lBu[64 * 128];  // 8 KB
  __shared__ __align__(16) char lBg[64 * 128];  // 8 KB

  int tid = threadIdx.x;
  int wave = tid >> 6, lane = tid & 63;
  int q = lane >> 4, mr = lane & 15;

  f32x4 accU[2][4] = {};
  f32x4 accG[2][4] = {};

  for (int k0 = 0; k0 < H_DIM; k0 += 64) {
    __syncthreads();
    stage_tile(A + k0, H_DIM, lA, wave, lane);   // 4 loads/wave
    stage64(BU + k0, H_DIM, lBu, wave, lane);    // 2 loads/wave
    stage64(BG + k0, H_DIM, lBg, wave, lane);    // 2 loads/wave
    __syncthreads();
    for (int s = 0; s < 2; ++s) {
      bf16x8 af[2], bu[4], bg[4];
      for (int mt = 0; mt < 2; ++mt)
        af[mt] = read_frag(lA, wave * 32 + mt * 16 + mr, s, q);
      for (int nt = 0; nt < 4; ++nt) {
        bu[nt] = read_frag(lBu, nt * 16 + mr, s, q);
        bg[nt] = read_frag(lBg, nt * 16 + mr, s, q);
      }
      for (int mt = 0; mt < 2; ++mt)
        for (int nt = 0; nt < 4; ++nt) {
          accU[mt][nt] = __builtin_amdgcn_mfma_f32_16x16x32_bf16(
              af[mt], bu[nt], accU[mt][nt], 0, 0, 0);
          accG[mt][nt] = __builtin_amdgcn_mfma_f32_16x16x32_bf16(
              af[mt], bg[nt], accG[mt][nt], 0, 0, 0);
        }
    }
  }

  int fl = *flag;
  int rbase = r0 + wave * 32;
  for (int nt = 0; nt < 4; ++nt) {
    int col = n0 + nt * 16 + mr;
    float bu_v, bg_v;
    if (fl) {
      bu_v = b2f(((const uint16_t*)buRaw)[(size_t)e * F_DIM + col]);
      bg_v = b2f(((const uint16_t*)bgRaw)[(size_t)e * F_DIM + col]);
    } else {
      bu_v = ((const float*)buRaw)[(size_t)e * F_DIM + col];
      bg_v = ((const float*)bgRaw)[(size_t)e * F_DIM + col];
    }
    for (int mt = 0; mt < 2; ++mt) {
      int r = rbase + mt * 16 + q * 4;
      for (int rg = 0; rg < 4; ++rg) {
        float u = accU[mt][nt][rg] + bu_v;
        float v = accG[mt][nt][rg] + bg_v;
        float s = v / (1.f + expf(-v));  // silu
        phi[(size_t)(r + rg) * F_DIM + col] = f2b(s * u);
      }
    }
  }
}

// ------------- down GEMM: Yrows = phi@Wd + bd (fp32 rows, NO atomics) ------
// R9 geometry (BM=BN=128, 4 waves, 32KB LDS); (256,3): acc 64 + ~100 fits
// the 170-reg budget -> 3 blocks/CU without meaningful spill.
__global__ __launch_bounds__(256, 3) void gemm_down(
    const uint16_t* __restrict__ phi, const uint16_t* __restrict__ WtD,
    const void* __restrict__ bdRaw, const int* __restrict__ flag,
    const int* __restrict__ tile_e, const int* __restrict__ tile_row,
    const int* __restrict__ ntiles, float* __restrict__ Yrows) {
  int ty = blockIdx.y;
  if (ty >= *ntiles) return;
  int e = tile_e[ty];
  int r0 = tile_row[ty];
  int n0 = blockIdx.x * 128;
  const uint16_t* A = phi + (size_t)r0 * F_DIM;
  const uint16_t* B = WtD + (size_t)e * H_DIM * F_DIM + (size_t)n0 * F_DIM;

  __shared__ __align__(16) char lA[128 * 128];
  __shared__ __align__(16) char lB[128 * 128];

  int tid = threadIdx.x;
  int wave = tid >> 6, lane = tid & 63;
  int wm = wave >> 1, wn = wave & 1;
  int q = lane >> 4, mr = lane & 15;

  f32x4 acc[4][4] = {};

  for (int k0 = 0; k0 < F_DIM; k0 += 64) {
    __syncthreads();
    stage_tile(A + k0, F_DIM, lA, wave, lane);
    stage_tile(B + k0, F_DIM, lB, wave, lane);
    __syncthreads();
    for (int s = 0; s < 2; ++s) {
      bf16x8 af[4], bf[4];
      for (int mt = 0; mt < 4; ++mt)
        af[mt] = read_frag(lA, wm * 64 + mt * 16 + mr, s, q);
      for (int nt = 0; nt < 4; ++nt)
        bf[nt] = read_frag(lB, wn * 64 + nt * 16 + mr, s, q);
      for (int mt = 0; mt < 4; ++mt)
        for (int nt = 0; nt < 4; ++nt)
          acc[mt][nt] = __builtin_amdgcn_mfma_f32_16x16x32_bf16(
              af[mt], bf[nt], acc[mt][nt], 0, 0, 0);
    }
  }

  int fl = *flag;
  int rbase = r0 + wm * 64;
  int cbase = n0 + wn * 64;
  for (int nt = 0; nt < 4; ++nt) {
    int col = cbase + nt * 16 + mr;
    float bd_v = fl ? b2f(((const uint16_t*)bdRaw)[(size_t)e * H_DIM + col])
                    : ((const float*)bdRaw)[(size_t)e * H_DIM + col];
    for (int mt = 0; mt < 4; ++mt) {
      int r = rbase + mt * 16 + q * 4;
      for (int rg = 0; rg < 4; ++rg)
        Yrows[(size_t)(r + rg) * H_DIM + col] = acc[mt][nt][rg] + bd_v;
    }
  }
}

// ---------------- combine: out[t] = w0*Y[r0] + w1*Y[r1] ---------------------
__global__ __launch_bounds__(256) void combine_kernel(
    const float* __restrict__ Y, const int* __restrict__ row_of,
    const float* __restrict__ top_w, const int* __restrict__ flag,
    void* __restrict__ out) {
  int t = blockIdx.x;
  int r0 = row_of[2 * t], r1 = row_of[2 * t + 1];
  float w0 = top_w[2 * t], w1 = top_w[2 * t + 1];
  int i = threadIdx.x;
  float4 a = ((const float4*)(Y + (size_t)r0 * H_DIM))[i];
  float4 b = ((const float4*)(Y + (size_t)r1 * H_DIM))[i];
  float4 o;
  o.x = w0 * a.x + w1 * b.x;
  o.y = w0 * a.y + w1 * b.y;
  o.z = w0 * a.z + w1 * b.z;
  o.w = w0 * a.w + w1 * b.w;
  if (*flag) {
    uint2 p;
    p.x = (uint32_t)f2b(o.x) | ((uint32_t)f2b(o.y) << 16);
    p.y = (uint32_t)f2b(o.z) | ((uint32_t)f2b(o.w) << 16);
    ((uint2*)out)[(size_t)t * 256 + i] = p;
  } else {
    ((float4*)out)[(size_t)t * 256 + i] = o;
  }
}

extern "C" void kernel_launch(void* const* d_in, const int* in_sizes, int n_in,
                              void* d_out, int out_size, void* d_ws, size_t ws_size,
                              hipStream_t stream) {
  const void* x = d_in[0];
  const void* gw = d_in[1];
  const void* w_up = d_in[2];
  const void* w_gate = d_in[3];
  const void* w_down = d_in[4];
  const void* b_up = d_in[5];
  const void* b_gate = d_in[6];
  const void* b_down = d_in[7];

  char* ws = (char*)d_ws;
  size_t off = 0;
  auto alloc = [&](size_t bytes) -> void* {
    void* p = ws + off;
    off += (bytes + 255) & ~(size_t)255;
    return p;
  };
  int* counts = (int*)alloc(32);
  int* bases = (int*)alloc(32);
  int* flag = (int*)alloc(32);
  int* ntiles = (int*)alloc(32);
  int* tile_e = (int*)alloc(sizeof(int) * MAXT);
  int* tile_row = (int*)alloc(sizeof(int) * MAXT);
  int* top_i = (int*)alloc(sizeof(int) * N_TOK * 2);
  float* top_w = (float*)alloc(sizeof(float) * N_TOK * 2);
  int* row_of = (int*)alloc(sizeof(int) * N_TOK * 2);
  uint16_t* Xg = (uint16_t*)alloc((size_t)RCAP * H_DIM * 2);
  uint16_t* phi = (uint16_t*)alloc((size_t)RCAP * F_DIM * 2);
  uint16_t* WtU = (uint16_t*)alloc((size_t)E_NUM * H_DIM * F_DIM * 2);
  uint16_t* WtG = (uint16_t*)alloc((size_t)E_NUM * H_DIM * F_DIM * 2);
  float* Yrows = (float*)alloc((size_t)RCAP * H_DIM * sizeof(float));

  detect_kernel<<<1, 256, 0, stream>>>((const uint16_t*)x, flag);
  router_kernel<<<N_TOK / 4, 256, 0, stream>>>(x, gw, flag, d_out, top_i,
                                               top_w);
  histscan_kernel<<<1, 1024, 0, stream>>>(top_i, counts, bases, row_of,
                                          tile_e, tile_row, ntiles);
  gather_kernel<<<N_TOK, 256, 0, stream>>>(x, flag, row_of, Xg);

  // up + gate transposes fused into one launch (z<8: up, z>=8: gate)
  transpose_kernel<<<dim3(F_DIM / 64, H_DIM / 64, 2 * E_NUM), 256, 0,
                     stream>>>(w_up, w_gate, flag, WtU, WtG, H_DIM, F_DIM);

  gemm_upgate<<<dim3(F_DIM / 64, MAXT), 256, 0, stream>>>(
      Xg, WtU, WtG, b_up, b_gate, flag, tile_e, tile_row, ntiles, phi);

  // down transpose reuses WtU buffer (WtG unused from here on)
  transpose_kernel<<<dim3(H_DIM / 64, F_DIM / 64, E_NUM), 256, 0, stream>>>(
      w_down, w_down, flag, WtU, WtU, F_DIM, H_DIM);
  gemm_down<<<dim3(H_DIM / 128, MAXT), 256, 0, stream>>>(
      phi, WtU, b_down, flag, tile_e, tile_row, ntiles, Yrows);

  combine_kernel<<<N_TOK, 256, 0, stream>>>(Yrows, row_of, top_w, flag, d_out);
}